// Round 12
// baseline (2057.611 us; speedup 1.0000x reference)
//
#include <hip/hip_runtime.h>
#include <cstdint>

#define NBATCH 16
#define NPOINT 1024
#define NPTS   100000
#define GPB    16            // blocks per batch
#define TPB    256           // threads per block (4 waves)
#define WPB    4
#define NSUB   16            // sub-blocks per batch in precompute kernels
#define STRIDE (GPB * TPB)   // 4096 threads per batch
#define KPT    25            // points per thread
#define NPAIR  13            // KPT as float pairs (last half-padded)

typedef unsigned long long u64;

// d_ws layout (no host memset needed):
//   @0    : float psum[16][16][4]  (4 KB) — per-(batch,sub) partial coord sums (plain stores)
//   @4096 : uint  pmax[16][16]     (1 KB) — per-(batch,sub) partial max sq-radius (plain stores)
//   @8192 : u64   slots[2][16][16] (4 KB) — per-(parity,batch,block) argmax msg (r7 layout);
//                                           zeroed by max_kernel block 0 (poisoned seq would
//                                           false-accept, so this clear is mandatory)

// ---------------- precompute 1: per-(batch,sub) coordinate sums ----------------
__global__ __launch_bounds__(256) void sum_kernel(const float* __restrict__ xyz,
                                                  float* __restrict__ psum) {
    const int b   = blockIdx.x & 15;
    const int sub = blockIdx.x >> 4;          // 0..15
    const float* P = xyz + (size_t)b * NPTS * 3;
    float sx = 0.f, sy = 0.f, sz = 0.f;
    for (int i = sub * TPB + threadIdx.x; i < NPTS; i += NSUB * TPB) {
        sx += P[i * 3 + 0];
        sy += P[i * 3 + 1];
        sz += P[i * 3 + 2];
    }
    #pragma unroll
    for (int off = 32; off; off >>= 1) {
        sx += __shfl_xor(sx, off);
        sy += __shfl_xor(sy, off);
        sz += __shfl_xor(sz, off);
    }
    __shared__ float r[3][4];
    const int wave = threadIdx.x >> 6, lane = threadIdx.x & 63;
    if (lane == 0) { r[0][wave] = sx; r[1][wave] = sy; r[2][wave] = sz; }
    __syncthreads();
    if (threadIdx.x == 0) {
        float* o = psum + (b * NSUB + sub) * 4;
        o[0] = r[0][0] + r[0][1] + r[0][2] + r[0][3];
        o[1] = r[1][0] + r[1][1] + r[1][2] + r[1][3];
        o[2] = r[2][0] + r[2][1] + r[2][2] + r[2][3];
    }
}

// -------- precompute 2: per-(batch,sub) max squared radius + slot clear --------
__global__ __launch_bounds__(256) void max_kernel(const float* __restrict__ xyz,
                                                  const float* __restrict__ psum,
                                                  unsigned* __restrict__ pmax,
                                                  u64* __restrict__ slots) {
    if (blockIdx.x == 0) {                    // clear the 512 message slots (2 per thread)
        slots[threadIdx.x] = 0ull;
        slots[threadIdx.x + 256] = 0ull;
    }
    const int b   = blockIdx.x & 15;
    const int sub = blockIdx.x >> 4;
    const float* P = xyz + (size_t)b * NPTS * 3;
    float sx = 0.f, sy = 0.f, sz = 0.f;
    #pragma unroll
    for (int s = 0; s < NSUB; ++s) {          // fixed order: deterministic mean for all blocks
        sx += psum[(b * NSUB + s) * 4 + 0];
        sy += psum[(b * NSUB + s) * 4 + 1];
        sz += psum[(b * NSUB + s) * 4 + 2];
    }
    const float mx = sx / (float)NPTS, my = sy / (float)NPTS, mz = sz / (float)NPTS;
    float best = 0.f;
    for (int i = sub * TPB + threadIdx.x; i < NPTS; i += NSUB * TPB) {
        float dx = P[i * 3 + 0] - mx;
        float dy = P[i * 3 + 1] - my;
        float dz = P[i * 3 + 2] - mz;
        best = fmaxf(best, dx * dx + dy * dy + dz * dz);
    }
    #pragma unroll
    for (int off = 32; off; off >>= 1) best = fmaxf(best, __shfl_xor(best, off));
    __shared__ float r[4];
    const int wave = threadIdx.x >> 6, lane = threadIdx.x & 63;
    if (lane == 0) r[wave] = best;
    __syncthreads();
    if (threadIdx.x == 0)
        pmax[b * NSUB + sub] = __float_as_uint(fmaxf(fmaxf(r[0], r[1]), fmaxf(r[2], r[3])));
}

// ---------------- main: FPS, barrier-free block interior + r7 global protocol ----------------
// Global message: [63:54] seq (=i+1), [53:22] distbits, [21:0] 0x3FFFFF - idx.
// LDS mailboxes (parity-buffered, seq-tagged — no __syncthreads in the loop):
//   wkey[p][w] = key | seq<<54      (wave w's block-local key for parity p)
//   wres[p][j] = val | seq<<32      (j=0: idx, 1..3: x/y/z bits — winner poller writes)
// Overwrite-safety (lag<=1, LDS): wave w writes wkey(i+2) only after passing wres-spin(i),
// which exists only after wave 0 consumed wkey(i). Wave 0 writes wres(i+2) only after
// consuming wkey(i+2), which needs waves past wres-spin(i+1). Global gate proof as r7.
__global__ __launch_bounds__(256, 1) void fps_kernel(const float* __restrict__ xyz,
                                                     const float* __restrict__ cmap,
                                                     const int* __restrict__ init_far,
                                                     const unsigned* __restrict__ pmax,
                                                     u64* __restrict__ slots,
                                                     float* __restrict__ out) {
    const int b   = blockIdx.x & 15;   // batch
    const int g   = blockIdx.x >> 4;   // block-in-batch 0..15
    const int tid = threadIdx.x;
    const int wave = tid >> 6, lane = tid & 63;
    const int tl  = g * TPB + tid;     // batch-local lane 0..4095
    const float* P = xyz + (size_t)b * NPTS * 3;

    // s_obj: deterministic reduce over the 16 partial maxes
    float m0 = 0.f;
    #pragma unroll
    for (int s = 0; s < NSUB; ++s) m0 = fmaxf(m0, __uint_as_float(pmax[b * NSUB + s]));
    const float sb = sqrtf(m0);

    // register-resident points (pairs, SLP-vectorizes to v_pk_* fp32) + running distances
    float pxx[NPAIR], pxy[NPAIR], pyx[NPAIR], pyy[NPAIR],
          pzx[NPAIR], pzy[NPAIR], pdx[NPAIR], pdy[NPAIR];
    #pragma unroll
    for (int j = 0; j < NPAIR; ++j) {
        const int p0 = tl + (2 * j) * STRIDE;
        const int p1 = tl + (2 * j + 1) * STRIDE;
        const bool v0 = p0 < NPTS, v1 = p1 < NPTS;
        pxx[j] = v0 ? P[p0 * 3 + 0] : 0.f;  pxy[j] = v1 ? P[p1 * 3 + 0] : 0.f;
        pyx[j] = v0 ? P[p0 * 3 + 1] : 0.f;  pyy[j] = v1 ? P[p1 * 3 + 1] : 0.f;
        pzx[j] = v0 ? P[p0 * 3 + 2] : 0.f;  pzy[j] = v1 ? P[p1 * 3 + 2] : 0.f;
        pdx[j] = v0 ? 1e10f : -1.0f;        pdy[j] = v1 ? 1e10f : -1.0f;
        // every lane owns >=24 valid points -> per-lane best always >= 0
    }

    __shared__ u64 wkey[2][WPB];       // parity x wave mailbox
    __shared__ u64 wres[2][4];         // parity x {idx,x,y,z} result mailbox
    __shared__ int curhist[NPOINT];    // full selection history (for the output pass)

    if (tid < 8)  wkey[tid >> 2][tid & 3] = 0ull;
    if (tid >= 8 && tid < 16) wres[(tid - 8) >> 2][tid & 3] = 0ull;
    __syncthreads();                   // mailboxes initialized (once)

    int cur = init_far[b];
    float cx = P[cur * 3 + 0], cy = P[cur * 3 + 1], cz = P[cur * 3 + 2];

    for (int i = 0; i < NPOINT; ++i) {
        if (tid == 192) curhist[i] = cur;          // wave 3, LDS only — off critical path
        if (i == NPOINT - 1) break;

        // ---- distance update + per-lane argmax (exact fp order match: no fma/contract) ----
        float best = -1.0f;
        int bidx = 0;
        {
            #pragma clang fp contract(off)
            #pragma unroll
            for (int j = 0; j < NPAIR; ++j) {
                float dx0 = pxx[j] - cx, dx1 = pxy[j] - cx;
                float dy0 = pyx[j] - cy, dy1 = pyy[j] - cy;
                float dz0 = pzx[j] - cz, dz1 = pzy[j] - cz;
                float s0 = dx0 * dx0 + dy0 * dy0;  float s1 = dx1 * dx1 + dy1 * dy1;
                s0 = s0 + dz0 * dz0;               s1 = s1 + dz1 * dz1;
                float n0 = fminf(pdx[j], s0);      float n1 = fminf(pdy[j], s1);
                pdx[j] = n0;                       pdy[j] = n1;
                if (n0 > best) { best = n0; bidx = tl + (2 * j) * STRIDE; }      // strict >
                if (n1 > best) { best = n1; bidx = tl + (2 * j + 1) * STRIDE; }  // => first max
            }
        }

        // ---- wave argmax (u64 butterfly; inverted idx -> smallest index on ties) ----
        const u64 want = (u64)(i + 1);             // fits in the 10-bit seq field (<=1023)
        const unsigned want32 = (unsigned)want;
        u64 key = ((u64)__float_as_uint(best) << 22) | (u64)(0x3FFFFFu - (unsigned)bidx);
        #pragma unroll
        for (int off = 32; off; off >>= 1) {
            u64 o2 = __shfl_xor(key, off);
            key = o2 > key ? o2 : key;
        }

        // publish this wave's key to the LDS mailbox immediately (no barrier)
        u64* const wk = &wkey[i & 1][0];
        if (lane == 0)
            __hip_atomic_store(&wk[wave], key | (want << 54),
                               __ATOMIC_RELAXED, __HIP_MEMORY_SCOPE_WORKGROUP);

        u64* const bs = slots + ((size_t)(i & 1) * NBATCH + b) * GPB;

        if (wave == 0) {
            // spin-collect the 4 wave keys from LDS (lanes 0..3)
            u64 kv = 0;
            if (lane < WPB) {
                for (;;) {
                    kv = __hip_atomic_load(&wk[lane], __ATOMIC_RELAXED,
                                           __HIP_MEMORY_SCOPE_WORKGROUP);
                    if ((kv >> 54) >= want) break;
                }
            }
            u64 bk = kv;
            #pragma unroll
            for (int off = 1; off < WPB; off <<= 1) {   // 2-hop max over lanes 0..3
                u64 o2 = __shfl_xor(bk, off);
                bk = o2 > bk ? o2 : bk;
            }
            if (lane == 0)
                __hip_atomic_store(&bs[g], (bk & 0x003FFFFFFFFFFFFFull) | (want << 54),
                                   __ATOMIC_RELAXED, __HIP_MEMORY_SCOPE_AGENT);

            // global poll (r7 protocol): one atomic load + one waitcnt per round
            u64 v = 0;
            if (lane < GPB) {
                u64* sp = &bs[lane];
                int tries = 0;
                for (;;) {
                    v = __hip_atomic_load(sp, __ATOMIC_RELAXED, __HIP_MEMORY_SCOPE_AGENT);
                    if ((v >> 54) >= want) break;
                    if (++tries > 16) __builtin_amdgcn_s_sleep(1);
                }
            }
            // prefetch candidate coords (L2-hot) BEFORE the reduce — hides the tail gather
            const int ci = (int)(0x3FFFFFu - (unsigned)(v & 0x3FFFFFu));
            float gx = 0.f, gy = 0.f, gz = 0.f;
            if (lane < GPB) {
                gx = P[ci * 3 + 0];
                gy = P[ci * 3 + 1];
                gz = P[ci * 3 + 2];
            }
            u64 kk = v;
            #pragma unroll
            for (int off = 8; off; off >>= 1) {     // 4-hop argmax over the 16 gate words
                u64 o2 = __shfl_xor(kk, off);
                kk = o2 > kk ? o2 : kk;
            }
            // winner poller lane publishes the result mailbox (4 seq-tagged words)
            const bool win = (lane < GPB) && (v == kk);   // exactly one lane
            if (win) {
                u64* wr = &wres[i & 1][0];
                __hip_atomic_store(&wr[0], (u64)(unsigned)ci | ((u64)want32 << 32),
                                   __ATOMIC_RELAXED, __HIP_MEMORY_SCOPE_WORKGROUP);
                __hip_atomic_store(&wr[1], (u64)__float_as_uint(gx) | ((u64)want32 << 32),
                                   __ATOMIC_RELAXED, __HIP_MEMORY_SCOPE_WORKGROUP);
                __hip_atomic_store(&wr[2], (u64)__float_as_uint(gy) | ((u64)want32 << 32),
                                   __ATOMIC_RELAXED, __HIP_MEMORY_SCOPE_WORKGROUP);
                __hip_atomic_store(&wr[3], (u64)__float_as_uint(gz) | ((u64)want32 << 32),
                                   __ATOMIC_RELAXED, __HIP_MEMORY_SCOPE_WORKGROUP);
            }
            // wave 0 takes the result straight from the winner lane (no LDS read)
            const int wl = __ffsll(__ballot(win)) - 1;
            cur = __shfl(ci, wl);
            cx  = __shfl(gx, wl);
            cy  = __shfl(gy, wl);
            cz  = __shfl(gz, wl);
        } else {
            // waves 1..3: spin on the result mailbox (released the instant it lands)
            u64 r = 0;
            if (lane < 4) {
                u64* wr = &wres[i & 1][0];
                for (;;) {
                    r = __hip_atomic_load(&wr[lane], __ATOMIC_RELAXED,
                                          __HIP_MEMORY_SCOPE_WORKGROUP);
                    if ((unsigned)(r >> 32) == want32) break;
                }
            }
            const unsigned lo = (unsigned)r;
            cur = (int)__shfl((int)lo, 0);
            cx  = __uint_as_float(__shfl(lo, 1));
            cy  = __uint_as_float(__shfl(lo, 2));
            cz  = __uint_as_float(__shfl(lo, 3));
        }
    }

    // ---------------- deferred output pass: 64 rows per block ----------------
    __syncthreads();                   // curhist fully written (wave 3's last write)
    if (tid < 64) {
        const int row = g * 64 + tid;  // 16 blocks x 64 rows = 1024
        const int c   = curhist[row];
        const float cm = cmap[(size_t)b * NPTS + c];
        const float x = P[c * 3 + 0], y = P[c * 3 + 1], z = P[c * 3 + 2];
        float* o = out + ((size_t)b * NPOINT + row) * 4;
        o[0] = cm;
        o[1] = x / sb;
        o[2] = y / sb;
        o[3] = z / sb;
    }
}

extern "C" void kernel_launch(void* const* d_in, const int* in_sizes, int n_in,
                              void* d_out, int out_size, void* d_ws, size_t ws_size,
                              hipStream_t stream) {
    const float* mesh = (const float*)d_in[0];
    const float* cmap = (const float*)d_in[1];
    const int* init   = (const int*)d_in[2];
    float* out = (float*)d_out;

    char* ws      = (char*)d_ws;
    float* psum   = (float*)ws;
    unsigned* pmx = (unsigned*)(ws + 4096);
    u64* slots    = (u64*)(ws + 8192);

    sum_kernel<<<dim3(256), dim3(TPB), 0, stream>>>(mesh, psum);
    max_kernel<<<dim3(256), dim3(TPB), 0, stream>>>(mesh, psum, pmx, slots);
    fps_kernel<<<dim3(256), dim3(TPB), 0, stream>>>(mesh, cmap, init, pmx, slots, out);
}